// Round 10
// baseline (594.249 us; speedup 1.0000x reference)
//
#include <hip/hip_runtime.h>
#include <stdint.h>

#define XD 1024
#define NS 65536
#define SPB 16
#define N1 256
#define N2 64

#if __has_builtin(__builtin_amdgcn_exp2f)
#define EXP2F(x) __builtin_amdgcn_exp2f(x)
#else
#define EXP2F(x) exp2f(x)
#endif
#if __has_builtin(__builtin_amdgcn_logf)
#define LOG2F(x) __builtin_amdgcn_logf(x)
#else
#define LOG2F(x) log2f(x)
#endif
#if __has_builtin(__builtin_amdgcn_rcpf)
#define RCPF(x) __builtin_amdgcn_rcpf(x)
#else
#define RCPF(x) (1.0f/(x))
#endif

typedef __attribute__((ext_vector_type(8))) short short8;
typedef __attribute__((ext_vector_type(4))) float float4v;
typedef __attribute__((ext_vector_type(2))) float float2v;

#define LOG2E 1.4426950408889634f
#define LN2   0.6931471805599453f
#define NL2LN2 0.5287663729448977f

// pk layout (shorts): [0 .. 131071]   W3 frags (2 mats x 64 cc x 2 kh x 64 lanes x 8)
//                     [131072 .. ]    W2 B-frags (2 mats x 4 cw x 8 ks x 64 lanes x 8)
#define PK2_OFF 131072

static __device__ __forceinline__ float tanh_fast(float x){
  float e = EXP2F(x * 2.8853900817779268f);   // e^(2x)
  return (e - 1.0f) * RCPF(e + 1.0f);
}
static __device__ __forceinline__ unsigned short f2bf(float x){
  union { float f; uint32_t u; } c; c.f = x;
  uint32_t u = c.u;
  return (unsigned short)((u + 0x7FFFu + ((u >> 16) & 1u)) >> 16);
}
static __device__ __forceinline__ float2v exp2p(float2v e){
  float2v r; r.x = EXP2F(e.x); r.y = EXP2F(e.y); return r;
}

// log2(j!) for j=0..19 (runtime table only needs 0..9 for data!)
#define G2TAB_INIT {0.0f,0.0f,1.0f,2.5849625007f,4.5849625007f,6.9068905956f, \
  9.4918530963f,12.2992080189f,15.2992080189f,18.4691332114f,21.7910613063f, \
  25.2504929251f,28.8354554258f,32.5358951439f,36.3432500660f,40.2501406616f, \
  44.2501406616f,48.3376035030f,52.5075285040f,56.7554560173f}

// Pack W3 [64][1024] and W2 [256][64] (fp32 row-major) into bf16 MFMA frag order.
__global__ void pack_weights(const float* __restrict__ W3r, const float* __restrict__ W3v,
                             const float* __restrict__ W2r, const float* __restrict__ W2v,
                             unsigned short* __restrict__ pk){
  int tid = blockIdx.x * 256 + threadIdx.x;   // 0..20479
  unsigned short t[8];
  if (tid < 16384){
    int mat  = tid >> 13;
    int cc   = (tid >> 7) & 63;
    int kh   = (tid >> 6) & 1;
    int l    = tid & 63;
    int col  = cc * 16 + (l & 15);
    const float* W3 = mat ? W3v : W3r;
    int kbase = kh * 32 + (l >> 4) * 8;
    #pragma unroll
    for (int j = 0; j < 8; ++j) t[j] = f2bf(W3[(size_t)(kbase + j) * XD + col]);
    uint4 val;
    val.x = (uint32_t)t[0] | ((uint32_t)t[1] << 16);
    val.y = (uint32_t)t[2] | ((uint32_t)t[3] << 16);
    val.z = (uint32_t)t[4] | ((uint32_t)t[5] << 16);
    val.w = (uint32_t)t[6] | ((uint32_t)t[7] << 16);
    *(uint4*)(pk + (size_t)tid * 8) = val;
  } else {
    int t2 = tid - 16384;                     // 0..4095
    int mat = t2 >> 11;
    int cw  = (t2 >> 9) & 3;
    int ks  = (t2 >> 6) & 7;
    int l   = t2 & 63;
    const float* W2 = mat ? W2v : W2r;
    int kbase = ks * 32 + (l >> 4) * 8;
    int col = cw * 16 + (l & 15);
    #pragma unroll
    for (int j = 0; j < 8; ++j) t[j] = f2bf(W2[(size_t)(kbase + j) * N2 + col]);
    uint4 val;
    val.x = (uint32_t)t[0] | ((uint32_t)t[1] << 16);
    val.y = (uint32_t)t[2] | ((uint32_t)t[3] << 16);
    val.z = (uint32_t)t[4] | ((uint32_t)t[5] << 16);
    val.w = (uint32_t)t[6] | ((uint32_t)t[7] << 16);
    *(uint4*)(pk + (size_t)(PK2_OFF) + (size_t)t2 * 8) = val;
  }
}

__global__ __launch_bounds__(256, 6) void cmp_fused(
    const float* __restrict__ w,   const float* __restrict__ data,
    const float* __restrict__ W1r, const float* __restrict__ b1r,
    const float* __restrict__ b2r, const float* __restrict__ b3r,
    const float* __restrict__ W1v, const float* __restrict__ b1v,
    const float* __restrict__ b2v, const float* __restrict__ b3v,
    const unsigned short* __restrict__ pk,
    float* __restrict__ out)
{
  __shared__ float wtile[SPB][32];
  __shared__ __align__(16) unsigned short h1lds[SPB * 264];   // stride 264 (pad +8)
  __shared__ __align__(16) unsigned short h2lds[2][SPB * 72]; // stride 72 (pad +8)
  __shared__ float lgf2[20];
  __shared__ float redbuf[SPB];

  const float G2tab[20] = G2TAB_INIT;

  int tid = threadIdx.x;
  int s0  = blockIdx.x * SPB;
  int lane = tid & 63;
  int wv_id = tid >> 6;
  int quad = lane >> 4;
  int mrow = lane & 15;

  if (tid < 20)  lgf2[tid] = G2tab[tid];
  if (tid < SPB) redbuf[tid] = 0.0f;
  #pragma unroll
  for (int i = 0; i < 2; ++i)
    ((float*)wtile)[tid + 256 * i] = w[(size_t)s0 * 32 + tid + 256 * i];
  __syncthreads();

  // ---------------- phase 1: MLP layers 1-2 ----------------
  const short8* B2p = (const short8*)(pk + PK2_OFF);
  for (int mat = 0; mat < 2; ++mat){
    const float* W1 = mat ? W1v : W1r;
    const float* b1 = mat ? b1v : b1r;
    const float* b2 = mat ? b2v : b2r;
    // layer1 (fp32 VALU): thread = output unit u (256), loop over 16 samples
    {
      int u = tid;
      float w1reg[16];
      #pragma unroll
      for (int k = 0; k < 16; ++k) w1reg[k] = W1[k * N1 + u];
      float bu = b1[u];
      int c0 = mat ? 2 : 0;   // rate uses w chunks {0,1,4,5}; v uses {2,3,6,7}
      for (int s = 0; s < SPB; ++s){
        const float4v* wr = (const float4v*)&wtile[s][0];
        float4v a = wr[c0], b = wr[c0 + 1], c = wr[c0 + 4], d = wr[c0 + 5];
        float acc = bu;
        acc = fmaf(a.x, w1reg[0],  acc); acc = fmaf(a.y, w1reg[1],  acc);
        acc = fmaf(a.z, w1reg[2],  acc); acc = fmaf(a.w, w1reg[3],  acc);
        acc = fmaf(b.x, w1reg[4],  acc); acc = fmaf(b.y, w1reg[5],  acc);
        acc = fmaf(b.z, w1reg[6],  acc); acc = fmaf(b.w, w1reg[7],  acc);
        acc = fmaf(c.x, w1reg[8],  acc); acc = fmaf(c.y, w1reg[9],  acc);
        acc = fmaf(c.z, w1reg[10], acc); acc = fmaf(c.w, w1reg[11], acc);
        acc = fmaf(d.x, w1reg[12], acc); acc = fmaf(d.y, w1reg[13], acc);
        acc = fmaf(d.z, w1reg[14], acc); acc = fmaf(d.w, w1reg[15], acc);
        h1lds[s * 264 + u] = f2bf(tanh_fast(acc));
      }
    }
    __syncthreads();
    // layer2 (MFMA): wave wv_id -> n-chunk cw (16 units). M=16 samples, K=256.
    {
      int cw = wv_id;
      float4v acc = {0,0,0,0};
      #pragma unroll
      for (int ks = 0; ks < 8; ++ks){
        short8 bfr = B2p[(size_t)((mat * 4 + cw) * 8 + ks) * 64 + lane];
        short8 a = *(const short8*)&h1lds[mrow * 264 + ks * 32 + quad * 8];
        acc = __builtin_amdgcn_mfma_f32_16x16x32_bf16(a, bfr, acc, 0, 0, 0);
      }
      float b2n = b2[cw * 16 + mrow];
      #pragma unroll
      for (int r = 0; r < 4; ++r){
        int sample = quad * 4 + r;
        h2lds[mat][sample * 72 + cw * 16 + mrow] = f2bf(tanh_fast(acc[r] + b2n));
      }
    }
    __syncthreads();
  }

  // ---------------- phase 2: layer3 MFMA (A=W3, B=h2) + packed elementwise ----
  // B-frag: h2[k=unit][n=sample]; lane holds n=mrow (one sample), k=quad*8+j
  short8 bh[2][2];   // [mat][k-half]
  #pragma unroll
  for (int mat = 0; mat < 2; ++mat)
    #pragma unroll
    for (int kh = 0; kh < 2; ++kh)
      bh[mat][kh] = *(const short8*)&h2lds[mat][mrow * 72 + kh * 32 + quad * 8];

  float2v accp[2] = {{0, 0}, {0, 0}};   // per-pair log2-domain logpmf sums
  const short8* Bp = (const short8*)pk;
  const float* drow = data + (size_t)(s0 + mrow) * XD;

  // prefetch pipeline registers for iteration 0 (W3 frags + data only;
  // b3r/b3v are 4KB L2-resident, loaded in-loop to save 8 VGPRs)
  int cc0 = wv_id * 16;
  short8 ar0 = Bp[(size_t)(cc0 * 2 + 0) * 64 + lane];
  short8 ar1 = Bp[(size_t)(cc0 * 2 + 1) * 64 + lane];
  short8 av0 = Bp[(size_t)((64 + cc0) * 2 + 0) * 64 + lane];
  short8 av1 = Bp[(size_t)((64 + cc0) * 2 + 1) * 64 + lane];
  float4v dv = *(const float4v*)(drow + cc0 * 16 + quad * 4);

  for (int it = 0; it < 16; ++it){
    // stash current, prefetch next (uniform branch)
    short8 car0 = ar0, car1 = ar1, cav0 = av0, cav1 = av1;
    float4v cdv = dv;
    int colq = (wv_id * 16 + it) * 16 + quad * 4;
    if (it < 15){
      int cc = wv_id * 16 + it + 1;
      ar0 = Bp[(size_t)(cc * 2 + 0) * 64 + lane];
      ar1 = Bp[(size_t)(cc * 2 + 1) * 64 + lane];
      av0 = Bp[(size_t)((64 + cc) * 2 + 0) * 64 + lane];
      av1 = Bp[(size_t)((64 + cc) * 2 + 1) * 64 + lane];
      dv  = *(const float4v*)(drow + cc * 16 + quad * 4);
    }
    float4v cr = {0,0,0,0}, cv = {0,0,0,0};
    cr = __builtin_amdgcn_mfma_f32_16x16x32_bf16(car0, bh[0][0], cr, 0, 0, 0);
    cr = __builtin_amdgcn_mfma_f32_16x16x32_bf16(car1, bh[0][1], cr, 0, 0, 0);
    cv = __builtin_amdgcn_mfma_f32_16x16x32_bf16(cav0, bh[1][0], cv, 0, 0, 0);
    cv = __builtin_amdgcn_mfma_f32_16x16x32_bf16(cav1, bh[1][1], cv, 0, 0, 0);
    float4v b3rv = *(const float4v*)(b3r + colq);
    float4v b3vv = *(const float4v*)(b3v + colq);
    // process the 4 columns as 2 packed pairs -> v_pk_* on the full-rate ops
    #pragma unroll
    for (int p = 0; p < 2; ++p){
      float2v d2 = {cdv[2*p],   cdv[2*p+1]};
      float2v yr = {cr[2*p] + b3rv[2*p], cr[2*p+1] + b3rv[2*p+1]};
      float2v yv = {cv[2*p] + b3vv[2*p], cv[2*p+1] + b3vv[2*p+1]};
      // L2 = -log2(softplus(yr)); stable log2-domain softplus, packed
      float2v er;
      er.x = EXP2F(-fabsf(yr.x) * LOG2E);
      er.y = EXP2F(-fabsf(yr.y) * LOG2E);
      float2v l1r; l1r.x = LOG2F(1.0f + er.x); l1r.y = LOG2F(1.0f + er.y);
      float2v myr = {fmaxf(yr.x, 0.0f), fmaxf(yr.y, 0.0f)};
      float2v spbr = myr * LOG2E + l1r;
      float2v L2;
      L2.x = NL2LN2 - LOG2F(spbr.x);
      L2.y = NL2LN2 - LOG2F(spbr.y);
      float2v ev;
      ev.x = EXP2F(-fabsf(yv.x) * LOG2E);
      ev.y = EXP2F(-fabsf(yv.y) * LOG2E);
      float2v l1v; l1v.x = LOG2F(1.0f + ev.x); l1v.y = LOG2F(1.0f + ev.y);
      float2v myv = {fmaxf(yv.x, 0.0f), fmaxf(yv.y, 0.0f)};
      float2v v = (myv * LOG2E + l1v) * LN2;     // natural softplus
      // Z = sum_j rate^j (j!)^-v via TWO seeded prime-power chains:
      // chain A: j=0..9 from t1=rate; chain B: j=10..19 from direct seed
      // t10 = exp2(10*L2 + nv*log2(10!)). rq_j = rate * j^-v (independent muls).
      float2v nv = -v;
      float2v rate = exp2p(L2);
      float2v q2  = exp2p(nv);
      float2v q3  = exp2p(nv * 1.58496250f);
      float2v q5  = exp2p(nv * 2.32192809f);
      float2v q7  = exp2p(nv * 2.80735492f);
      float2v q11 = exp2p(nv * 3.45943162f);
      float2v q13 = exp2p(nv * 3.70043972f);
      float2v q17 = exp2p(nv * 4.08746284f);
      float2v q19 = exp2p(nv * 4.24792751f);
      float2v t10 = exp2p(L2 * 10.0f + nv * 21.7910613f);   // rate^10 * (10!)^-v
      float2v rq2  = rate * q2,  rq3  = rate * q3,  rq5  = rate * q5,  rq7 = rate * q7;
      float2v rq11 = rate * q11, rq13 = rate * q13, rq17 = rate * q17, rq19 = rate * q19;
      float2v rq4  = rq2 * q2,  rq6  = rq2 * q3,  rq8  = rq4 * q2,  rq9  = rq3 * q3;
      float2v rq12 = rq4 * q3,  rq14 = rq2 * q7,  rq15 = rq3 * q5;
      float2v rq16 = rq8 * q2,  rq18 = rq9 * q2;
      // chain A: terms j=0..9
      float2v tA = rate;
      float2v ZA = tA + 1.0f;
      tA *= rq2;  ZA += tA;
      tA *= rq3;  ZA += tA;
      tA *= rq4;  ZA += tA;
      tA *= rq5;  ZA += tA;
      tA *= rq6;  ZA += tA;
      tA *= rq7;  ZA += tA;
      tA *= rq8;  ZA += tA;
      tA *= rq9;  ZA += tA;      // j=9
      // chain B: terms j=10..19
      float2v tB = t10;
      float2v ZB = tB;
      tB *= rq11; ZB += tB;
      tB *= rq12; ZB += tB;
      tB *= rq13; ZB += tB;
      tB *= rq14; ZB += tB;
      tB *= rq15; ZB += tB;
      tB *= rq16; ZB += tB;
      tB *= rq17; ZB += tB;
      tB *= rq18; ZB += tB;
      tB *= rq19; ZB += tB;      // j=19
      float2v Z = ZA + ZB;
      float2v lZ;  lZ.x = LOG2F(Z.x);  lZ.y = LOG2F(Z.y);
      float2v vlg; vlg.x = lgf2[(int)d2.x]; vlg.y = lgf2[(int)d2.y];
      // log2-scaled logpmf: d*L2 - v*log2(d!) - log2Z
      accp[p] += d2 * L2 - v * vlg - lZ;
    }
  }

  // per-lane: sum pairs; cross-quad via shuffle; cross-wave via LDS atomics
  float local = (accp[0].x + accp[0].y) + (accp[1].x + accp[1].y);
  local += __shfl_xor(local, 16);
  local += __shfl_xor(local, 32);
  if (quad == 0) atomicAdd(&redbuf[mrow], local);
  __syncthreads();
  if (tid < SPB) out[s0 + tid] = redbuf[tid] * (-LN2 / 1024.0f);
}

extern "C" void kernel_launch(void* const* d_in, const int* in_sizes, int n_in,
                              void* d_out, int out_size, void* d_ws, size_t ws_size,
                              hipStream_t stream){
  const float* w    = (const float*)d_in[0];
  const float* data = (const float*)d_in[1];
  const float* W1r  = (const float*)d_in[2];
  const float* b1r  = (const float*)d_in[3];
  const float* W2r  = (const float*)d_in[4];
  const float* b2r  = (const float*)d_in[5];
  const float* W3r  = (const float*)d_in[6];
  const float* b3r  = (const float*)d_in[7];
  const float* W1v  = (const float*)d_in[8];
  const float* b1v  = (const float*)d_in[9];
  const float* W2v  = (const float*)d_in[10];
  const float* b2v  = (const float*)d_in[11];
  const float* W3v  = (const float*)d_in[12];
  const float* b3v  = (const float*)d_in[13];
  unsigned short* pk = (unsigned short*)d_ws;   // 256KB W3 frags + 64KB W2 frags
  float* out = (float*)d_out;

  hipLaunchKernelGGL(pack_weights, dim3(80), dim3(256), 0, stream, W3r, W3v, W2r, W2v, pk);
  hipLaunchKernelGGL(cmp_fused, dim3(NS / SPB), dim3(256), 0, stream,
                     w, data, W1r, b1r, b2r, b3r,
                     W1v, b1v, b2v, b3v, pk, out);
}

// Round 11
// 582.510 us; speedup vs baseline: 1.0202x; 1.0202x over previous
//
#include <hip/hip_runtime.h>
#include <stdint.h>

#define XD 1024
#define NS 65536
#define SPB 16
#define N1 256
#define N2 64

#if __has_builtin(__builtin_amdgcn_exp2f)
#define EXP2F(x) __builtin_amdgcn_exp2f(x)
#else
#define EXP2F(x) exp2f(x)
#endif
#if __has_builtin(__builtin_amdgcn_logf)
#define LOG2F(x) __builtin_amdgcn_logf(x)
#else
#define LOG2F(x) log2f(x)
#endif
#if __has_builtin(__builtin_amdgcn_rcpf)
#define RCPF(x) __builtin_amdgcn_rcpf(x)
#else
#define RCPF(x) (1.0f/(x))
#endif

typedef __attribute__((ext_vector_type(8))) short short8;
typedef __attribute__((ext_vector_type(4))) float float4v;
typedef __attribute__((ext_vector_type(2))) float float2v;

#define LOG2E 1.4426950408889634f
#define LN2   0.6931471805599453f
#define NL2LN2 0.5287663729448977f

// pk layout (shorts): [0 .. 131071]   W3 frags (2 mats x 64 cc x 2 kh x 64 lanes x 8)
//                     [131072 .. ]    W2 B-frags (2 mats x 4 cw x 8 ks x 64 lanes x 8)
#define PK2_OFF 131072

static __device__ __forceinline__ float tanh_fast(float x){
  float e = EXP2F(x * 2.8853900817779268f);   // e^(2x)
  return (e - 1.0f) * RCPF(e + 1.0f);
}
static __device__ __forceinline__ unsigned short f2bf(float x){
  union { float f; uint32_t u; } c; c.f = x;
  uint32_t u = c.u;
  return (unsigned short)((u + 0x7FFFu + ((u >> 16) & 1u)) >> 16);
}
static __device__ __forceinline__ float2v exp2p(float2v e){
  float2v r; r.x = EXP2F(e.x); r.y = EXP2F(e.y); return r;
}

// log2(j!) for j=0..19 (runtime table only needs 0..9 for data!)
#define G2TAB_INIT {0.0f,0.0f,1.0f,2.5849625007f,4.5849625007f,6.9068905956f, \
  9.4918530963f,12.2992080189f,15.2992080189f,18.4691332114f,21.7910613063f, \
  25.2504929251f,28.8354554258f,32.5358951439f,36.3432500660f,40.2501406616f, \
  44.2501406616f,48.3376035030f,52.5075285040f,56.7554560173f}

// Pack W3 [64][1024] and W2 [256][64] (fp32 row-major) into bf16 MFMA frag order.
__global__ void pack_weights(const float* __restrict__ W3r, const float* __restrict__ W3v,
                             const float* __restrict__ W2r, const float* __restrict__ W2v,
                             unsigned short* __restrict__ pk){
  int tid = blockIdx.x * 256 + threadIdx.x;   // 0..20479
  unsigned short t[8];
  if (tid < 16384){
    int mat  = tid >> 13;
    int cc   = (tid >> 7) & 63;
    int kh   = (tid >> 6) & 1;
    int l    = tid & 63;
    int col  = cc * 16 + (l & 15);
    const float* W3 = mat ? W3v : W3r;
    int kbase = kh * 32 + (l >> 4) * 8;
    #pragma unroll
    for (int j = 0; j < 8; ++j) t[j] = f2bf(W3[(size_t)(kbase + j) * XD + col]);
    uint4 val;
    val.x = (uint32_t)t[0] | ((uint32_t)t[1] << 16);
    val.y = (uint32_t)t[2] | ((uint32_t)t[3] << 16);
    val.z = (uint32_t)t[4] | ((uint32_t)t[5] << 16);
    val.w = (uint32_t)t[6] | ((uint32_t)t[7] << 16);
    *(uint4*)(pk + (size_t)tid * 8) = val;
  } else {
    int t2 = tid - 16384;                     // 0..4095
    int mat = t2 >> 11;
    int cw  = (t2 >> 9) & 3;
    int ks  = (t2 >> 6) & 7;
    int l   = t2 & 63;
    const float* W2 = mat ? W2v : W2r;
    int kbase = ks * 32 + (l >> 4) * 8;
    int col = cw * 16 + (l & 15);
    #pragma unroll
    for (int j = 0; j < 8; ++j) t[j] = f2bf(W2[(size_t)(kbase + j) * N2 + col]);
    uint4 val;
    val.x = (uint32_t)t[0] | ((uint32_t)t[1] << 16);
    val.y = (uint32_t)t[2] | ((uint32_t)t[3] << 16);
    val.z = (uint32_t)t[4] | ((uint32_t)t[5] << 16);
    val.w = (uint32_t)t[6] | ((uint32_t)t[7] << 16);
    *(uint4*)(pk + (size_t)(PK2_OFF) + (size_t)t2 * 8) = val;
  }
}

__global__ __launch_bounds__(256, 6) void cmp_fused(
    const float* __restrict__ w,   const float* __restrict__ data,
    const float* __restrict__ W1r, const float* __restrict__ b1r,
    const float* __restrict__ b2r, const float* __restrict__ b3r,
    const float* __restrict__ W1v, const float* __restrict__ b1v,
    const float* __restrict__ b2v, const float* __restrict__ b3v,
    const unsigned short* __restrict__ pk,
    float* __restrict__ out)
{
  __shared__ float wtile[SPB][32];
  __shared__ __align__(16) unsigned short h1lds[SPB * 264];   // stride 264 (pad +8)
  __shared__ __align__(16) unsigned short h2lds[2][SPB * 72]; // stride 72 (pad +8)
  __shared__ float lgf2[20];
  __shared__ float redbuf[SPB];

  const float G2tab[20] = G2TAB_INIT;

  int tid = threadIdx.x;
  int s0  = blockIdx.x * SPB;
  int lane = tid & 63;
  int wv_id = tid >> 6;
  int quad = lane >> 4;
  int mrow = lane & 15;

  if (tid < 20)  lgf2[tid] = G2tab[tid];
  if (tid < SPB) redbuf[tid] = 0.0f;
  #pragma unroll
  for (int i = 0; i < 2; ++i)
    ((float*)wtile)[tid + 256 * i] = w[(size_t)s0 * 32 + tid + 256 * i];
  __syncthreads();

  // ---------------- phase 1: MLP layers 1-2 ----------------
  const short8* B2p = (const short8*)(pk + PK2_OFF);
  for (int mat = 0; mat < 2; ++mat){
    const float* W1 = mat ? W1v : W1r;
    const float* b1 = mat ? b1v : b1r;
    const float* b2 = mat ? b2v : b2r;
    // layer1 (fp32 VALU): thread = output unit u (256), loop over 16 samples
    {
      int u = tid;
      float w1reg[16];
      #pragma unroll
      for (int k = 0; k < 16; ++k) w1reg[k] = W1[k * N1 + u];
      float bu = b1[u];
      int c0 = mat ? 2 : 0;   // rate uses w chunks {0,1,4,5}; v uses {2,3,6,7}
      for (int s = 0; s < SPB; ++s){
        const float4v* wr = (const float4v*)&wtile[s][0];
        float4v a = wr[c0], b = wr[c0 + 1], c = wr[c0 + 4], d = wr[c0 + 5];
        float acc = bu;
        acc = fmaf(a.x, w1reg[0],  acc); acc = fmaf(a.y, w1reg[1],  acc);
        acc = fmaf(a.z, w1reg[2],  acc); acc = fmaf(a.w, w1reg[3],  acc);
        acc = fmaf(b.x, w1reg[4],  acc); acc = fmaf(b.y, w1reg[5],  acc);
        acc = fmaf(b.z, w1reg[6],  acc); acc = fmaf(b.w, w1reg[7],  acc);
        acc = fmaf(c.x, w1reg[8],  acc); acc = fmaf(c.y, w1reg[9],  acc);
        acc = fmaf(c.z, w1reg[10], acc); acc = fmaf(c.w, w1reg[11], acc);
        acc = fmaf(d.x, w1reg[12], acc); acc = fmaf(d.y, w1reg[13], acc);
        acc = fmaf(d.z, w1reg[14], acc); acc = fmaf(d.w, w1reg[15], acc);
        h1lds[s * 264 + u] = f2bf(tanh_fast(acc));
      }
    }
    __syncthreads();
    // layer2 (MFMA): wave wv_id -> n-chunk cw (16 units). M=16 samples, K=256.
    {
      int cw = wv_id;
      float4v acc = {0,0,0,0};
      #pragma unroll
      for (int ks = 0; ks < 8; ++ks){
        short8 bfr = B2p[(size_t)((mat * 4 + cw) * 8 + ks) * 64 + lane];
        short8 a = *(const short8*)&h1lds[mrow * 264 + ks * 32 + quad * 8];
        acc = __builtin_amdgcn_mfma_f32_16x16x32_bf16(a, bfr, acc, 0, 0, 0);
      }
      float b2n = b2[cw * 16 + mrow];
      #pragma unroll
      for (int r = 0; r < 4; ++r){
        int sample = quad * 4 + r;
        h2lds[mat][sample * 72 + cw * 16 + mrow] = f2bf(tanh_fast(acc[r] + b2n));
      }
    }
    __syncthreads();
  }

  // ---------------- phase 2: layer3 MFMA (A=W3, B=h2) + packed elementwise ----
  // B-frag: h2[k=unit][n=sample]; lane holds n=mrow (one sample), k=quad*8+j
  short8 bh[2][2];   // [mat][k-half]
  #pragma unroll
  for (int mat = 0; mat < 2; ++mat)
    #pragma unroll
    for (int kh = 0; kh < 2; ++kh)
      bh[mat][kh] = *(const short8*)&h2lds[mat][mrow * 72 + kh * 32 + quad * 8];

  float2v accp[2] = {{0, 0}, {0, 0}};   // per-pair log2-domain logpmf sums
  const short8* Bp = (const short8*)pk;
  const float* drow = data + (size_t)(s0 + mrow) * XD;

  // No register prefetch pipeline: at 6 blocks/CU (24 waves) TLP covers the
  // L2-resident frag loads and the data stream; saves ~24 VGPRs -> no spill
  // at the (256,6) budget.
  for (int it = 0; it < 16; ++it){
    // wave owns a contiguous 256-col band: adjacent its share 128B data lines
    int cc = wv_id * 16 + it;
    short8 ar0 = Bp[(size_t)(cc * 2 + 0) * 64 + lane];
    short8 ar1 = Bp[(size_t)(cc * 2 + 1) * 64 + lane];
    short8 av0 = Bp[(size_t)((64 + cc) * 2 + 0) * 64 + lane];
    short8 av1 = Bp[(size_t)((64 + cc) * 2 + 1) * 64 + lane];
    int colq = cc * 16 + quad * 4;
    float4v dv = *(const float4v*)(drow + colq);
    float4v cr = {0,0,0,0}, cv = {0,0,0,0};
    cr = __builtin_amdgcn_mfma_f32_16x16x32_bf16(ar0, bh[0][0], cr, 0, 0, 0);
    cr = __builtin_amdgcn_mfma_f32_16x16x32_bf16(ar1, bh[0][1], cr, 0, 0, 0);
    cv = __builtin_amdgcn_mfma_f32_16x16x32_bf16(av0, bh[1][0], cv, 0, 0, 0);
    cv = __builtin_amdgcn_mfma_f32_16x16x32_bf16(av1, bh[1][1], cv, 0, 0, 0);
    float4v b3rv = *(const float4v*)(b3r + colq);
    float4v b3vv = *(const float4v*)(b3v + colq);
    // process the 4 columns as 2 packed pairs -> v_pk_* on the full-rate ops
    #pragma unroll
    for (int p = 0; p < 2; ++p){
      float2v d2 = {dv[2*p],   dv[2*p+1]};
      float2v yr = {cr[2*p] + b3rv[2*p], cr[2*p+1] + b3rv[2*p+1]};
      float2v yv = {cv[2*p] + b3vv[2*p], cv[2*p+1] + b3vv[2*p+1]};
      // L2 = -log2(softplus(yr)); stable log2-domain softplus, packed
      float2v er;
      er.x = EXP2F(-fabsf(yr.x) * LOG2E);
      er.y = EXP2F(-fabsf(yr.y) * LOG2E);
      float2v l1r; l1r.x = LOG2F(1.0f + er.x); l1r.y = LOG2F(1.0f + er.y);
      float2v myr = {fmaxf(yr.x, 0.0f), fmaxf(yr.y, 0.0f)};
      float2v spbr = myr * LOG2E + l1r;
      float2v L2;
      L2.x = NL2LN2 - LOG2F(spbr.x);
      L2.y = NL2LN2 - LOG2F(spbr.y);
      float2v ev;
      ev.x = EXP2F(-fabsf(yv.x) * LOG2E);
      ev.y = EXP2F(-fabsf(yv.y) * LOG2E);
      float2v l1v; l1v.x = LOG2F(1.0f + ev.x); l1v.y = LOG2F(1.0f + ev.y);
      float2v myv = {fmaxf(yv.x, 0.0f), fmaxf(yv.y, 0.0f)};
      float2v v = (myv * LOG2E + l1v) * LN2;     // natural softplus
      // Z = sum_j rate^j (j!)^-v via TWO seeded prime-power chains:
      // chain A: j=0..9 from t1=rate; chain B: j=10..19 seeded by
      // t10 = exp2(10*L2 + nv*log2(10!)). rq_j = rate * j^-v (independent muls).
      float2v nv = -v;
      float2v rate = exp2p(L2);
      float2v q2  = exp2p(nv);
      float2v q3  = exp2p(nv * 1.58496250f);
      float2v q5  = exp2p(nv * 2.32192809f);
      float2v q7  = exp2p(nv * 2.80735492f);
      float2v q11 = exp2p(nv * 3.45943162f);
      float2v q13 = exp2p(nv * 3.70043972f);
      float2v q17 = exp2p(nv * 4.08746284f);
      float2v q19 = exp2p(nv * 4.24792751f);
      float2v t10 = exp2p(L2 * 10.0f + nv * 21.7910613f);   // rate^10 * (10!)^-v
      float2v rq2  = rate * q2,  rq3  = rate * q3,  rq5  = rate * q5,  rq7 = rate * q7;
      float2v rq11 = rate * q11, rq13 = rate * q13, rq17 = rate * q17, rq19 = rate * q19;
      float2v rq4  = rq2 * q2,  rq6  = rq2 * q3,  rq8  = rq4 * q2,  rq9  = rq3 * q3;
      float2v rq12 = rq4 * q3,  rq14 = rq2 * q7,  rq15 = rq3 * q5;
      float2v rq16 = rq8 * q2,  rq18 = rq9 * q2;
      // chain A: terms j=0..9
      float2v tA = rate;
      float2v ZA = tA + 1.0f;
      tA *= rq2;  ZA += tA;
      tA *= rq3;  ZA += tA;
      tA *= rq4;  ZA += tA;
      tA *= rq5;  ZA += tA;
      tA *= rq6;  ZA += tA;
      tA *= rq7;  ZA += tA;
      tA *= rq8;  ZA += tA;
      tA *= rq9;  ZA += tA;      // j=9
      // chain B: terms j=10..19
      float2v tB = t10;
      float2v ZB = tB;
      tB *= rq11; ZB += tB;
      tB *= rq12; ZB += tB;
      tB *= rq13; ZB += tB;
      tB *= rq14; ZB += tB;
      tB *= rq15; ZB += tB;
      tB *= rq16; ZB += tB;
      tB *= rq17; ZB += tB;
      tB *= rq18; ZB += tB;
      tB *= rq19; ZB += tB;      // j=19
      float2v Z = ZA + ZB;
      float2v lZ;  lZ.x = LOG2F(Z.x);  lZ.y = LOG2F(Z.y);
      float2v vlg; vlg.x = lgf2[(int)d2.x]; vlg.y = lgf2[(int)d2.y];
      // log2-scaled logpmf: d*L2 - v*log2(d!) - log2Z
      accp[p] += d2 * L2 - v * vlg - lZ;
    }
  }

  // per-lane: sum pairs; cross-quad via shuffle; cross-wave via LDS atomics
  float local = (accp[0].x + accp[0].y) + (accp[1].x + accp[1].y);
  local += __shfl_xor(local, 16);
  local += __shfl_xor(local, 32);
  if (quad == 0) atomicAdd(&redbuf[mrow], local);
  __syncthreads();
  if (tid < SPB) out[s0 + tid] = redbuf[tid] * (-LN2 / 1024.0f);
}

extern "C" void kernel_launch(void* const* d_in, const int* in_sizes, int n_in,
                              void* d_out, int out_size, void* d_ws, size_t ws_size,
                              hipStream_t stream){
  const float* w    = (const float*)d_in[0];
  const float* data = (const float*)d_in[1];
  const float* W1r  = (const float*)d_in[2];
  const float* b1r  = (const float*)d_in[3];
  const float* W2r  = (const float*)d_in[4];
  const float* b2r  = (const float*)d_in[5];
  const float* W3r  = (const float*)d_in[6];
  const float* b3r  = (const float*)d_in[7];
  const float* W1v  = (const float*)d_in[8];
  const float* b1v  = (const float*)d_in[9];
  const float* W2v  = (const float*)d_in[10];
  const float* b2v  = (const float*)d_in[11];
  const float* W3v  = (const float*)d_in[12];
  const float* b3v  = (const float*)d_in[13];
  unsigned short* pk = (unsigned short*)d_ws;   // 256KB W3 frags + 64KB W2 frags
  float* out = (float*)d_out;

  hipLaunchKernelGGL(pack_weights, dim3(80), dim3(256), 0, stream, W3r, W3v, W2r, W2v, pk);
  hipLaunchKernelGGL(cmp_fused, dim3(NS / SPB), dim3(256), 0, stream,
                     w, data, W1r, b1r, b2r, b3r,
                     W1v, b1v, b2v, b3v, pk, out);
}

// Round 12
// 497.400 us; speedup vs baseline: 1.1947x; 1.1711x over previous
//
#include <hip/hip_runtime.h>
#include <stdint.h>

#define XD 1024
#define NS 65536
#define SPB 16
#define N1 256
#define N2 64

#if __has_builtin(__builtin_amdgcn_exp2f)
#define EXP2F(x) __builtin_amdgcn_exp2f(x)
#else
#define EXP2F(x) exp2f(x)
#endif
#if __has_builtin(__builtin_amdgcn_logf)
#define LOG2F(x) __builtin_amdgcn_logf(x)
#else
#define LOG2F(x) log2f(x)
#endif
#if __has_builtin(__builtin_amdgcn_rcpf)
#define RCPF(x) __builtin_amdgcn_rcpf(x)
#else
#define RCPF(x) (1.0f/(x))
#endif

typedef __attribute__((ext_vector_type(8))) short short8;
typedef __attribute__((ext_vector_type(4))) float float4v;
typedef __attribute__((ext_vector_type(2))) float float2v;

#define LOG2E 1.4426950408889634f
#define LN2   0.6931471805599453f
#define NL2LN2 0.5287663729448977f

// pk layout (shorts): [0 .. 131071]   W3 frags (2 mats x 64 cc x 2 kh x 64 lanes x 8)
//                     [131072 .. ]    W2 B-frags (2 mats x 4 cw x 8 ks x 64 lanes x 8)
#define PK2_OFF 131072

static __device__ __forceinline__ float tanh_fast(float x){
  float e = EXP2F(x * 2.8853900817779268f);   // e^(2x)
  return (e - 1.0f) * RCPF(e + 1.0f);
}
static __device__ __forceinline__ unsigned short f2bf(float x){
  union { float f; uint32_t u; } c; c.f = x;
  uint32_t u = c.u;
  return (unsigned short)((u + 0x7FFFu + ((u >> 16) & 1u)) >> 16);
}
static __device__ __forceinline__ float2v exp2p(float2v e){
  float2v r; r.x = EXP2F(e.x); r.y = EXP2F(e.y); return r;
}

// log2(j!) for j=0..19 (runtime table only needs 0..9 for data!)
#define G2TAB_INIT {0.0f,0.0f,1.0f,2.5849625007f,4.5849625007f,6.9068905956f, \
  9.4918530963f,12.2992080189f,15.2992080189f,18.4691332114f,21.7910613063f, \
  25.2504929251f,28.8354554258f,32.5358951439f,36.3432500660f,40.2501406616f, \
  44.2501406616f,48.3376035030f,52.5075285040f,56.7554560173f}

// Pack W3 [64][1024] and W2 [256][64] (fp32 row-major) into bf16 MFMA frag order.
__global__ void pack_weights(const float* __restrict__ W3r, const float* __restrict__ W3v,
                             const float* __restrict__ W2r, const float* __restrict__ W2v,
                             unsigned short* __restrict__ pk){
  int tid = blockIdx.x * 256 + threadIdx.x;   // 0..20479
  unsigned short t[8];
  if (tid < 16384){
    int mat  = tid >> 13;
    int cc   = (tid >> 7) & 63;
    int kh   = (tid >> 6) & 1;
    int l    = tid & 63;
    int col  = cc * 16 + (l & 15);
    const float* W3 = mat ? W3v : W3r;
    int kbase = kh * 32 + (l >> 4) * 8;
    #pragma unroll
    for (int j = 0; j < 8; ++j) t[j] = f2bf(W3[(size_t)(kbase + j) * XD + col]);
    uint4 val;
    val.x = (uint32_t)t[0] | ((uint32_t)t[1] << 16);
    val.y = (uint32_t)t[2] | ((uint32_t)t[3] << 16);
    val.z = (uint32_t)t[4] | ((uint32_t)t[5] << 16);
    val.w = (uint32_t)t[6] | ((uint32_t)t[7] << 16);
    *(uint4*)(pk + (size_t)tid * 8) = val;
  } else {
    int t2 = tid - 16384;                     // 0..4095
    int mat = t2 >> 11;
    int cw  = (t2 >> 9) & 3;
    int ks  = (t2 >> 6) & 7;
    int l   = t2 & 63;
    const float* W2 = mat ? W2v : W2r;
    int kbase = ks * 32 + (l >> 4) * 8;
    int col = cw * 16 + (l & 15);
    #pragma unroll
    for (int j = 0; j < 8; ++j) t[j] = f2bf(W2[(size_t)(kbase + j) * N2 + col]);
    uint4 val;
    val.x = (uint32_t)t[0] | ((uint32_t)t[1] << 16);
    val.y = (uint32_t)t[2] | ((uint32_t)t[3] << 16);
    val.z = (uint32_t)t[4] | ((uint32_t)t[5] << 16);
    val.w = (uint32_t)t[6] | ((uint32_t)t[7] << 16);
    *(uint4*)(pk + (size_t)(PK2_OFF) + (size_t)t2 * 8) = val;
  }
}

__global__ __launch_bounds__(256, 6) void cmp_fused(
    const float* __restrict__ w,   const float* __restrict__ data,
    const float* __restrict__ W1r, const float* __restrict__ b1r,
    const float* __restrict__ b2r, const float* __restrict__ b3r,
    const float* __restrict__ W1v, const float* __restrict__ b1v,
    const float* __restrict__ b2v, const float* __restrict__ b3v,
    const unsigned short* __restrict__ pk,
    float* __restrict__ out)
{
  __shared__ float wtile[SPB][32];
  __shared__ __align__(16) unsigned short h1lds[SPB * 264];   // stride 264 (pad +8)
  __shared__ __align__(16) unsigned short h2lds[2][SPB * 72]; // stride 72 (pad +8)
  __shared__ float lgf2[20];
  __shared__ float redbuf[SPB];

  const float G2tab[20] = G2TAB_INIT;

  int tid = threadIdx.x;
  int s0  = blockIdx.x * SPB;
  int lane = tid & 63;
  int wv_id = tid >> 6;
  int quad = lane >> 4;
  int mrow = lane & 15;

  if (tid < 20)  lgf2[tid] = G2tab[tid];
  if (tid < SPB) redbuf[tid] = 0.0f;
  #pragma unroll
  for (int i = 0; i < 2; ++i)
    ((float*)wtile)[tid + 256 * i] = w[(size_t)s0 * 32 + tid + 256 * i];
  __syncthreads();

  // ---------------- phase 1: MLP layers 1-2 ----------------
  const short8* B2p = (const short8*)(pk + PK2_OFF);
  for (int mat = 0; mat < 2; ++mat){
    const float* W1 = mat ? W1v : W1r;
    const float* b1 = mat ? b1v : b1r;
    const float* b2 = mat ? b2v : b2r;
    // layer1 (fp32 VALU): thread = output unit u (256), loop over 16 samples
    {
      int u = tid;
      float w1reg[16];
      #pragma unroll
      for (int k = 0; k < 16; ++k) w1reg[k] = W1[k * N1 + u];
      float bu = b1[u];
      int c0 = mat ? 2 : 0;   // rate uses w chunks {0,1,4,5}; v uses {2,3,6,7}
      for (int s = 0; s < SPB; ++s){
        const float4v* wr = (const float4v*)&wtile[s][0];
        float4v a = wr[c0], b = wr[c0 + 1], c = wr[c0 + 4], d = wr[c0 + 5];
        float acc = bu;
        acc = fmaf(a.x, w1reg[0],  acc); acc = fmaf(a.y, w1reg[1],  acc);
        acc = fmaf(a.z, w1reg[2],  acc); acc = fmaf(a.w, w1reg[3],  acc);
        acc = fmaf(b.x, w1reg[4],  acc); acc = fmaf(b.y, w1reg[5],  acc);
        acc = fmaf(b.z, w1reg[6],  acc); acc = fmaf(b.w, w1reg[7],  acc);
        acc = fmaf(c.x, w1reg[8],  acc); acc = fmaf(c.y, w1reg[9],  acc);
        acc = fmaf(c.z, w1reg[10], acc); acc = fmaf(c.w, w1reg[11], acc);
        acc = fmaf(d.x, w1reg[12], acc); acc = fmaf(d.y, w1reg[13], acc);
        acc = fmaf(d.z, w1reg[14], acc); acc = fmaf(d.w, w1reg[15], acc);
        h1lds[s * 264 + u] = f2bf(tanh_fast(acc));
      }
    }
    __syncthreads();
    // layer2 (MFMA): wave wv_id -> n-chunk cw (16 units). M=16 samples, K=256.
    {
      int cw = wv_id;
      float4v acc = {0,0,0,0};
      #pragma unroll
      for (int ks = 0; ks < 8; ++ks){
        short8 bfr = B2p[(size_t)((mat * 4 + cw) * 8 + ks) * 64 + lane];
        short8 a = *(const short8*)&h1lds[mrow * 264 + ks * 32 + quad * 8];
        acc = __builtin_amdgcn_mfma_f32_16x16x32_bf16(a, bfr, acc, 0, 0, 0);
      }
      float b2n = b2[cw * 16 + mrow];
      #pragma unroll
      for (int r = 0; r < 4; ++r){
        int sample = quad * 4 + r;
        h2lds[mat][sample * 72 + cw * 16 + mrow] = f2bf(tanh_fast(acc[r] + b2n));
      }
    }
    __syncthreads();
  }

  // ---------------- phase 2: layer3 MFMA (A=W3, B=h2) + packed elementwise ----
  // B-frag: h2[k=unit][n=sample]; lane holds n=mrow (one sample), k=quad*8+j
  short8 bh[2][2];   // [mat][k-half]
  #pragma unroll
  for (int mat = 0; mat < 2; ++mat)
    #pragma unroll
    for (int kh = 0; kh < 2; ++kh)
      bh[mat][kh] = *(const short8*)&h2lds[mat][mrow * 72 + kh * 32 + quad * 8];

  float2v accp[2] = {{0, 0}, {0, 0}};   // per-pair log2-domain logpmf sums
  const short8* Bp = (const short8*)pk;
  const float* drow = data + (size_t)(s0 + mrow) * XD;

  for (int it = 0; it < 16; ++it){
    // wave owns a contiguous 256-col band: adjacent its share 128B data lines
    int cc = wv_id * 16 + it;
    short8 ar0 = Bp[(size_t)(cc * 2 + 0) * 64 + lane];
    short8 ar1 = Bp[(size_t)(cc * 2 + 1) * 64 + lane];
    short8 av0 = Bp[(size_t)((64 + cc) * 2 + 0) * 64 + lane];
    short8 av1 = Bp[(size_t)((64 + cc) * 2 + 1) * 64 + lane];
    int colq = cc * 16 + quad * 4;
    float4v dv = *(const float4v*)(drow + colq);
    float4v cr = {0,0,0,0}, cv = {0,0,0,0};
    cr = __builtin_amdgcn_mfma_f32_16x16x32_bf16(ar0, bh[0][0], cr, 0, 0, 0);
    cr = __builtin_amdgcn_mfma_f32_16x16x32_bf16(ar1, bh[0][1], cr, 0, 0, 0);
    cv = __builtin_amdgcn_mfma_f32_16x16x32_bf16(av0, bh[1][0], cv, 0, 0, 0);
    cv = __builtin_amdgcn_mfma_f32_16x16x32_bf16(av1, bh[1][1], cv, 0, 0, 0);
    // process the 4 columns as 2 packed pairs -> v_pk_* on the full-rate ops
    #pragma unroll
    for (int p = 0; p < 2; ++p){
      float2v b3rp = *(const float2v*)(b3r + colq + 2 * p);
      float2v b3vp = *(const float2v*)(b3v + colq + 2 * p);
      float2v d2 = {dv[2*p],   dv[2*p+1]};
      float2v yr = {cr[2*p] + b3rp.x, cr[2*p+1] + b3rp.y};
      float2v yv = {cv[2*p] + b3vp.x, cv[2*p+1] + b3vp.y};
      // L2 = -log2(softplus(yr)); stable log2-domain softplus, packed
      float2v er;
      er.x = EXP2F(-fabsf(yr.x) * LOG2E);
      er.y = EXP2F(-fabsf(yr.y) * LOG2E);
      float2v l1r; l1r.x = LOG2F(1.0f + er.x); l1r.y = LOG2F(1.0f + er.y);
      float2v myr = {fmaxf(yr.x, 0.0f), fmaxf(yr.y, 0.0f)};
      float2v spbr = myr * LOG2E + l1r;
      float2v L2;
      L2.x = NL2LN2 - LOG2F(spbr.x);
      L2.y = NL2LN2 - LOG2F(spbr.y);
      float2v ev;
      ev.x = EXP2F(-fabsf(yv.x) * LOG2E);
      ev.y = EXP2F(-fabsf(yv.y) * LOG2E);
      float2v l1v; l1v.x = LOG2F(1.0f + ev.x); l1v.y = LOG2F(1.0f + ev.y);
      float2v myv = {fmaxf(yv.x, 0.0f), fmaxf(yv.y, 0.0f)};
      float2v v = (myv * LOG2E + l1v) * LN2;     // natural softplus
      // Z = sum_j rate^j (j!)^-v via TWO seeded chains with ON-THE-FLY prime
      // factorization: step j multiplies by rate and the prime factors of j.
      // Only the 8 prime powers p^-v are ever live (16 VGPRs, vs 34 for the
      // rq-precompute form) -> fits the 6-block/CU register budget.
      float2v nv = -v;
      float2v rate = exp2p(L2);
      float2v q2  = exp2p(nv);
      float2v q3  = exp2p(nv * 1.58496250f);
      float2v q5  = exp2p(nv * 2.32192809f);
      float2v q7  = exp2p(nv * 2.80735492f);
      // chain A: j=0..9
      float2v tA = rate;                    // j=1
      float2v ZA = tA + 1.0f;
      tA *= rate; tA *= q2;                       ZA += tA;   // j=2
      tA *= rate; tA *= q3;                       ZA += tA;   // j=3
      tA *= rate; tA *= q2; tA *= q2;             ZA += tA;   // j=4
      tA *= rate; tA *= q5;                       ZA += tA;   // j=5
      tA *= rate; tA *= q2; tA *= q3;             ZA += tA;   // j=6
      tA *= rate; tA *= q7;                       ZA += tA;   // j=7
      tA *= rate; tA *= q2; tA *= q2; tA *= q2;   ZA += tA;   // j=8
      tA *= rate; tA *= q3; tA *= q3;             ZA += tA;   // j=9
      // chain B: j=10..19, seeded by t10 = exp2(10*L2 + nv*log2(10!))
      float2v q11 = exp2p(nv * 3.45943162f);
      float2v q13 = exp2p(nv * 3.70043972f);
      float2v q17 = exp2p(nv * 4.08746284f);
      float2v q19 = exp2p(nv * 4.24792751f);
      float2v tB = exp2p(L2 * 10.0f + nv * 21.7910613f);
      float2v ZB = tB;                      // j=10
      tB *= rate; tB *= q11;                          ZB += tB;  // j=11
      tB *= rate; tB *= q2; tB *= q2; tB *= q3;       ZB += tB;  // j=12
      tB *= rate; tB *= q13;                          ZB += tB;  // j=13
      tB *= rate; tB *= q2; tB *= q7;                 ZB += tB;  // j=14
      tB *= rate; tB *= q3; tB *= q5;                 ZB += tB;  // j=15
      tB *= rate; tB *= q2; tB *= q2; tB *= q2; tB *= q2; ZB += tB; // j=16
      tB *= rate; tB *= q17;                          ZB += tB;  // j=17
      tB *= rate; tB *= q2; tB *= q3; tB *= q3;       ZB += tB;  // j=18
      tB *= rate; tB *= q19;                          ZB += tB;  // j=19
      float2v Z = ZA + ZB;
      float2v lZ;  lZ.x = LOG2F(Z.x);  lZ.y = LOG2F(Z.y);
      float2v vlg; vlg.x = lgf2[(int)d2.x]; vlg.y = lgf2[(int)d2.y];
      // log2-scaled logpmf: d*L2 - v*log2(d!) - log2Z
      accp[p] += d2 * L2 - v * vlg - lZ;
    }
  }

  // per-lane: sum pairs; cross-quad via shuffle; cross-wave via LDS atomics
  float local = (accp[0].x + accp[0].y) + (accp[1].x + accp[1].y);
  local += __shfl_xor(local, 16);
  local += __shfl_xor(local, 32);
  if (quad == 0) atomicAdd(&redbuf[mrow], local);
  __syncthreads();
  if (tid < SPB) out[s0 + tid] = redbuf[tid] * (-LN2 / 1024.0f);
}

extern "C" void kernel_launch(void* const* d_in, const int* in_sizes, int n_in,
                              void* d_out, int out_size, void* d_ws, size_t ws_size,
                              hipStream_t stream){
  const float* w    = (const float*)d_in[0];
  const float* data = (const float*)d_in[1];
  const float* W1r  = (const float*)d_in[2];
  const float* b1r  = (const float*)d_in[3];
  const float* W2r  = (const float*)d_in[4];
  const float* b2r  = (const float*)d_in[5];
  const float* W3r  = (const float*)d_in[6];
  const float* b3r  = (const float*)d_in[7];
  const float* W1v  = (const float*)d_in[8];
  const float* b1v  = (const float*)d_in[9];
  const float* W2v  = (const float*)d_in[10];
  const float* b2v  = (const float*)d_in[11];
  const float* W3v  = (const float*)d_in[12];
  const float* b3v  = (const float*)d_in[13];
  unsigned short* pk = (unsigned short*)d_ws;   // 256KB W3 frags + 64KB W2 frags
  float* out = (float*)d_out;

  hipLaunchKernelGGL(pack_weights, dim3(80), dim3(256), 0, stream, W3r, W3v, W2r, W2v, pk);
  hipLaunchKernelGGL(cmp_fused, dim3(NS / SPB), dim3(256), 0, stream,
                     w, data, W1r, b1r, b2r, b3r,
                     W1v, b1v, b2v, b3v, pk, out);
}

// Round 13
// 482.892 us; speedup vs baseline: 1.2306x; 1.0300x over previous
//
#include <hip/hip_runtime.h>
#include <stdint.h>

#define XD 1024
#define NS 65536
#define SPB 16
#define N1 256
#define N2 64

#if __has_builtin(__builtin_amdgcn_exp2f)
#define EXP2F(x) __builtin_amdgcn_exp2f(x)
#else
#define EXP2F(x) exp2f(x)
#endif
#if __has_builtin(__builtin_amdgcn_logf)
#define LOG2F(x) __builtin_amdgcn_logf(x)
#else
#define LOG2F(x) log2f(x)
#endif
#if __has_builtin(__builtin_amdgcn_rcpf)
#define RCPF(x) __builtin_amdgcn_rcpf(x)
#else
#define RCPF(x) (1.0f/(x))
#endif

typedef __attribute__((ext_vector_type(8))) short short8;
typedef __attribute__((ext_vector_type(4))) float float4v;
typedef __attribute__((ext_vector_type(2))) float float2v;

#define LOG2E 1.4426950408889634f
#define LN2   0.6931471805599453f
#define NL2LN2 0.5287663729448977f

// pk layout (shorts): [0 .. 131071]   W3 frags (2 mats x 64 cc x 2 kh x 64 lanes x 8)
//                     [131072 .. ]    W2 B-frags (2 mats x 4 cw x 8 ks x 64 lanes x 8)
#define PK2_OFF 131072

static __device__ __forceinline__ float tanh_fast(float x){
  float e = EXP2F(x * 2.8853900817779268f);   // e^(2x)
  return (e - 1.0f) * RCPF(e + 1.0f);
}
static __device__ __forceinline__ unsigned short f2bf(float x){
  union { float f; uint32_t u; } c; c.f = x;
  uint32_t u = c.u;
  return (unsigned short)((u + 0x7FFFu + ((u >> 16) & 1u)) >> 16);
}
static __device__ __forceinline__ float2v exp2p(float2v e){
  float2v r; r.x = EXP2F(e.x); r.y = EXP2F(e.y); return r;
}

// log2(j!) for j=0..19 (runtime table only needs 0..9 for data!)
#define G2TAB_INIT {0.0f,0.0f,1.0f,2.5849625007f,4.5849625007f,6.9068905956f, \
  9.4918530963f,12.2992080189f,15.2992080189f,18.4691332114f,21.7910613063f, \
  25.2504929251f,28.8354554258f,32.5358951439f,36.3432500660f,40.2501406616f, \
  44.2501406616f,48.3376035030f,52.5075285040f,56.7554560173f}

// Pack W3 [64][1024] and W2 [256][64] (fp32 row-major) into bf16 MFMA frag order.
__global__ void pack_weights(const float* __restrict__ W3r, const float* __restrict__ W3v,
                             const float* __restrict__ W2r, const float* __restrict__ W2v,
                             unsigned short* __restrict__ pk){
  int tid = blockIdx.x * 256 + threadIdx.x;   // 0..20479
  unsigned short t[8];
  if (tid < 16384){
    int mat  = tid >> 13;
    int cc   = (tid >> 7) & 63;
    int kh   = (tid >> 6) & 1;
    int l    = tid & 63;
    int col  = cc * 16 + (l & 15);
    const float* W3 = mat ? W3v : W3r;
    int kbase = kh * 32 + (l >> 4) * 8;
    #pragma unroll
    for (int j = 0; j < 8; ++j) t[j] = f2bf(W3[(size_t)(kbase + j) * XD + col]);
    uint4 val;
    val.x = (uint32_t)t[0] | ((uint32_t)t[1] << 16);
    val.y = (uint32_t)t[2] | ((uint32_t)t[3] << 16);
    val.z = (uint32_t)t[4] | ((uint32_t)t[5] << 16);
    val.w = (uint32_t)t[6] | ((uint32_t)t[7] << 16);
    *(uint4*)(pk + (size_t)tid * 8) = val;
  } else {
    int t2 = tid - 16384;                     // 0..4095
    int mat = t2 >> 11;
    int cw  = (t2 >> 9) & 3;
    int ks  = (t2 >> 6) & 7;
    int l   = t2 & 63;
    const float* W2 = mat ? W2v : W2r;
    int kbase = ks * 32 + (l >> 4) * 8;
    int col = cw * 16 + (l & 15);
    #pragma unroll
    for (int j = 0; j < 8; ++j) t[j] = f2bf(W2[(size_t)(kbase + j) * N2 + col]);
    uint4 val;
    val.x = (uint32_t)t[0] | ((uint32_t)t[1] << 16);
    val.y = (uint32_t)t[2] | ((uint32_t)t[3] << 16);
    val.z = (uint32_t)t[4] | ((uint32_t)t[5] << 16);
    val.w = (uint32_t)t[6] | ((uint32_t)t[7] << 16);
    *(uint4*)(pk + (size_t)(PK2_OFF) + (size_t)t2 * 8) = val;
  }
}

__global__ __launch_bounds__(256, 5) void cmp_fused(
    const float* __restrict__ w,   const float* __restrict__ data,
    const float* __restrict__ W1r, const float* __restrict__ b1r,
    const float* __restrict__ b2r, const float* __restrict__ b3r,
    const float* __restrict__ W1v, const float* __restrict__ b1v,
    const float* __restrict__ b2v, const float* __restrict__ b3v,
    const unsigned short* __restrict__ pk,
    float* __restrict__ out)
{
  __shared__ float wtile[SPB][32];
  __shared__ __align__(16) unsigned short h1lds[SPB * 264];   // stride 264 (pad +8)
  __shared__ __align__(16) unsigned short h2lds[2][SPB * 72]; // stride 72 (pad +8)
  __shared__ float lgf2[20];
  __shared__ float redbuf[SPB];

  const float G2tab[20] = G2TAB_INIT;

  int tid = threadIdx.x;
  int s0  = blockIdx.x * SPB;
  int lane = tid & 63;
  int wv_id = tid >> 6;
  int quad = lane >> 4;
  int mrow = lane & 15;

  if (tid < 20)  lgf2[tid] = G2tab[tid];
  if (tid < SPB) redbuf[tid] = 0.0f;
  #pragma unroll
  for (int i = 0; i < 2; ++i)
    ((float*)wtile)[tid + 256 * i] = w[(size_t)s0 * 32 + tid + 256 * i];
  __syncthreads();

  // ---------------- phase 1: MLP layers 1-2 ----------------
  const short8* B2p = (const short8*)(pk + PK2_OFF);
  for (int mat = 0; mat < 2; ++mat){
    const float* W1 = mat ? W1v : W1r;
    const float* b1 = mat ? b1v : b1r;
    const float* b2 = mat ? b2v : b2r;
    // layer1 (fp32 VALU): thread = output unit u (256), loop over 16 samples
    {
      int u = tid;
      float w1reg[16];
      #pragma unroll
      for (int k = 0; k < 16; ++k) w1reg[k] = W1[k * N1 + u];
      float bu = b1[u];
      int c0 = mat ? 2 : 0;   // rate uses w chunks {0,1,4,5}; v uses {2,3,6,7}
      for (int s = 0; s < SPB; ++s){
        const float4v* wr = (const float4v*)&wtile[s][0];
        float4v a = wr[c0], b = wr[c0 + 1], c = wr[c0 + 4], d = wr[c0 + 5];
        float acc = bu;
        acc = fmaf(a.x, w1reg[0],  acc); acc = fmaf(a.y, w1reg[1],  acc);
        acc = fmaf(a.z, w1reg[2],  acc); acc = fmaf(a.w, w1reg[3],  acc);
        acc = fmaf(b.x, w1reg[4],  acc); acc = fmaf(b.y, w1reg[5],  acc);
        acc = fmaf(b.z, w1reg[6],  acc); acc = fmaf(b.w, w1reg[7],  acc);
        acc = fmaf(c.x, w1reg[8],  acc); acc = fmaf(c.y, w1reg[9],  acc);
        acc = fmaf(c.z, w1reg[10], acc); acc = fmaf(c.w, w1reg[11], acc);
        acc = fmaf(d.x, w1reg[12], acc); acc = fmaf(d.y, w1reg[13], acc);
        acc = fmaf(d.z, w1reg[14], acc); acc = fmaf(d.w, w1reg[15], acc);
        h1lds[s * 264 + u] = f2bf(tanh_fast(acc));
      }
    }
    __syncthreads();
    // layer2 (MFMA): wave wv_id -> n-chunk cw (16 units). M=16 samples, K=256.
    {
      int cw = wv_id;
      float4v acc = {0,0,0,0};
      #pragma unroll
      for (int ks = 0; ks < 8; ++ks){
        short8 bfr = B2p[(size_t)((mat * 4 + cw) * 8 + ks) * 64 + lane];
        short8 a = *(const short8*)&h1lds[mrow * 264 + ks * 32 + quad * 8];
        acc = __builtin_amdgcn_mfma_f32_16x16x32_bf16(a, bfr, acc, 0, 0, 0);
      }
      float b2n = b2[cw * 16 + mrow];
      #pragma unroll
      for (int r = 0; r < 4; ++r){
        int sample = quad * 4 + r;
        h2lds[mat][sample * 72 + cw * 16 + mrow] = f2bf(tanh_fast(acc[r] + b2n));
      }
    }
    __syncthreads();
  }

  // ---------------- phase 2: layer3 MFMA (A=W3, B=h2) + packed elementwise ----
  // B-frag: h2[k=unit][n=sample]; lane holds n=mrow (one sample), k=quad*8+j
  short8 bh[2][2];   // [mat][k-half]
  #pragma unroll
  for (int mat = 0; mat < 2; ++mat)
    #pragma unroll
    for (int kh = 0; kh < 2; ++kh)
      bh[mat][kh] = *(const short8*)&h2lds[mat][mrow * 72 + kh * 32 + quad * 8];

  float2v accp[2] = {{0, 0}, {0, 0}};   // per-pair log2-domain logpmf sums
  const short8* Bp = (const short8*)pk;
  const float* drow = data + (size_t)(s0 + mrow) * XD;

  // prefetch pipeline registers for iteration 0
  int cc0 = wv_id * 16;
  short8 ar0 = Bp[(size_t)(cc0 * 2 + 0) * 64 + lane];
  short8 ar1 = Bp[(size_t)(cc0 * 2 + 1) * 64 + lane];
  short8 av0 = Bp[(size_t)((64 + cc0) * 2 + 0) * 64 + lane];
  short8 av1 = Bp[(size_t)((64 + cc0) * 2 + 1) * 64 + lane];
  int colq0 = cc0 * 16 + quad * 4;
  float4v b3rv = *(const float4v*)(b3r + colq0);
  float4v b3vv = *(const float4v*)(b3v + colq0);
  float4v dv   = *(const float4v*)(drow + colq0);

  for (int it = 0; it < 16; ++it){
    // stash current, prefetch next (uniform branch)
    short8 car0 = ar0, car1 = ar1, cav0 = av0, cav1 = av1;
    float4v cb3r = b3rv, cb3v = b3vv, cdv = dv;
    if (it < 15){
      int cc = wv_id * 16 + it + 1;
      ar0 = Bp[(size_t)(cc * 2 + 0) * 64 + lane];
      ar1 = Bp[(size_t)(cc * 2 + 1) * 64 + lane];
      av0 = Bp[(size_t)((64 + cc) * 2 + 0) * 64 + lane];
      av1 = Bp[(size_t)((64 + cc) * 2 + 1) * 64 + lane];
      int colq = cc * 16 + quad * 4;
      b3rv = *(const float4v*)(b3r + colq);
      b3vv = *(const float4v*)(b3v + colq);
      dv   = *(const float4v*)(drow + colq);
    }
    float4v cr = {0,0,0,0}, cv = {0,0,0,0};
    cr = __builtin_amdgcn_mfma_f32_16x16x32_bf16(car0, bh[0][0], cr, 0, 0, 0);
    cr = __builtin_amdgcn_mfma_f32_16x16x32_bf16(car1, bh[0][1], cr, 0, 0, 0);
    cv = __builtin_amdgcn_mfma_f32_16x16x32_bf16(cav0, bh[1][0], cv, 0, 0, 0);
    cv = __builtin_amdgcn_mfma_f32_16x16x32_bf16(cav1, bh[1][1], cv, 0, 0, 0);
    // process the 4 columns as 2 packed pairs -> v_pk_* on the full-rate ops
    #pragma unroll
    for (int p = 0; p < 2; ++p){
      float2v d2 = {cdv[2*p],   cdv[2*p+1]};
      float2v yr = {cr[2*p] + cb3r[2*p], cr[2*p+1] + cb3r[2*p+1]};
      float2v yv = {cv[2*p] + cb3v[2*p], cv[2*p+1] + cb3v[2*p+1]};
      // L2 = -log2(softplus(yr)); stable log2-domain softplus, packed
      float2v er;
      er.x = EXP2F(-fabsf(yr.x) * LOG2E);
      er.y = EXP2F(-fabsf(yr.y) * LOG2E);
      float2v l1r; l1r.x = LOG2F(1.0f + er.x); l1r.y = LOG2F(1.0f + er.y);
      float2v myr = {fmaxf(yr.x, 0.0f), fmaxf(yr.y, 0.0f)};
      float2v spbr = myr * LOG2E + l1r;
      float2v L2;
      L2.x = NL2LN2 - LOG2F(spbr.x);
      L2.y = NL2LN2 - LOG2F(spbr.y);
      float2v ev;
      ev.x = EXP2F(-fabsf(yv.x) * LOG2E);
      ev.y = EXP2F(-fabsf(yv.y) * LOG2E);
      float2v l1v; l1v.x = LOG2F(1.0f + ev.x); l1v.y = LOG2F(1.0f + ev.y);
      float2v myv = {fmaxf(yv.x, 0.0f), fmaxf(yv.y, 0.0f)};
      float2v v = (myv * LOG2E + l1v) * LN2;     // natural softplus
      // Z = sum_j rate^j (j!)^-v via TWO seeded prime-power chains:
      // chain A: j=0..9 from t1=rate; chain B: j=10..19 seeded by
      // t10 = exp2(10*L2 + nv*log2(10!)). rq_j = rate * j^-v (independent muls).
      float2v nv = -v;
      float2v rate = exp2p(L2);
      float2v q2  = exp2p(nv);
      float2v q3  = exp2p(nv * 1.58496250f);
      float2v q5  = exp2p(nv * 2.32192809f);
      float2v q7  = exp2p(nv * 2.80735492f);
      float2v q11 = exp2p(nv * 3.45943162f);
      float2v q13 = exp2p(nv * 3.70043972f);
      float2v q17 = exp2p(nv * 4.08746284f);
      float2v q19 = exp2p(nv * 4.24792751f);
      float2v t10 = exp2p(L2 * 10.0f + nv * 21.7910613f);   // rate^10 * (10!)^-v
      float2v rq2  = rate * q2,  rq3  = rate * q3,  rq5  = rate * q5,  rq7 = rate * q7;
      float2v rq11 = rate * q11, rq13 = rate * q13, rq17 = rate * q17, rq19 = rate * q19;
      float2v rq4  = rq2 * q2,  rq6  = rq2 * q3,  rq8  = rq4 * q2,  rq9  = rq3 * q3;
      float2v rq12 = rq4 * q3,  rq14 = rq2 * q7,  rq15 = rq3 * q5;
      float2v rq16 = rq8 * q2,  rq18 = rq9 * q2;
      // chain A: terms j=0..9
      float2v tA = rate;
      float2v ZA = tA + 1.0f;
      tA *= rq2;  ZA += tA;
      tA *= rq3;  ZA += tA;
      tA *= rq4;  ZA += tA;
      tA *= rq5;  ZA += tA;
      tA *= rq6;  ZA += tA;
      tA *= rq7;  ZA += tA;
      tA *= rq8;  ZA += tA;
      tA *= rq9;  ZA += tA;      // j=9
      // chain B: terms j=10..19
      float2v tB = t10;
      float2v ZB = tB;
      tB *= rq11; ZB += tB;
      tB *= rq12; ZB += tB;
      tB *= rq13; ZB += tB;
      tB *= rq14; ZB += tB;
      tB *= rq15; ZB += tB;
      tB *= rq16; ZB += tB;
      tB *= rq17; ZB += tB;
      tB *= rq18; ZB += tB;
      tB *= rq19; ZB += tB;      // j=19
      float2v Z = ZA + ZB;
      float2v lZ;  lZ.x = LOG2F(Z.x);  lZ.y = LOG2F(Z.y);
      float2v vlg; vlg.x = lgf2[(int)d2.x]; vlg.y = lgf2[(int)d2.y];
      // log2-scaled logpmf: d*L2 - v*log2(d!) - log2Z
      accp[p] += d2 * L2 - v * vlg - lZ;
    }
  }

  // per-lane: sum pairs; cross-quad via shuffle; cross-wave via LDS atomics
  float local = (accp[0].x + accp[0].y) + (accp[1].x + accp[1].y);
  local += __shfl_xor(local, 16);
  local += __shfl_xor(local, 32);
  if (quad == 0) atomicAdd(&redbuf[mrow], local);
  __syncthreads();
  if (tid < SPB) out[s0 + tid] = redbuf[tid] * (-LN2 / 1024.0f);
}

extern "C" void kernel_launch(void* const* d_in, const int* in_sizes, int n_in,
                              void* d_out, int out_size, void* d_ws, size_t ws_size,
                              hipStream_t stream){
  const float* w    = (const float*)d_in[0];
  const float* data = (const float*)d_in[1];
  const float* W1r  = (const float*)d_in[2];
  const float* b1r  = (const float*)d_in[3];
  const float* W2r  = (const float*)d_in[4];
  const float* b2r  = (const float*)d_in[5];
  const float* W3r  = (const float*)d_in[6];
  const float* b3r  = (const float*)d_in[7];
  const float* W1v  = (const float*)d_in[8];
  const float* b1v  = (const float*)d_in[9];
  const float* W2v  = (const float*)d_in[10];
  const float* b2v  = (const float*)d_in[11];
  const float* W3v  = (const float*)d_in[12];
  const float* b3v  = (const float*)d_in[13];
  unsigned short* pk = (unsigned short*)d_ws;   // 256KB W3 frags + 64KB W2 frags
  float* out = (float*)d_out;

  hipLaunchKernelGGL(pack_weights, dim3(80), dim3(256), 0, stream, W3r, W3v, W2r, W2v, pk);
  hipLaunchKernelGGL(cmp_fused, dim3(NS / SPB), dim3(256), 0, stream,
                     w, data, W1r, b1r, b2r, b3r,
                     W1v, b1v, b2v, b3v, pk, out);
}